// Round 2
// baseline (1539.256 us; speedup 1.0000x reference)
//
#include <hip/hip_runtime.h>
#include <stdint.h>

typedef unsigned short u16;
typedef unsigned int u32;
typedef short bf16x8 __attribute__((ext_vector_type(8)));
typedef float f32x4 __attribute__((ext_vector_type(4)));

#define DEV __device__ __forceinline__

DEV float bf2f(u16 u) { union { float f; u32 i; } x; x.i = ((u32)u) << 16; return x.f; }
DEV u16 f2bf(float f) {
  union { float f; u32 i; } x; x.f = f;
  u32 i = x.i;
  u32 r = (i + 0x7fffu + ((i >> 16) & 1u)) >> 16;  // RTNE
  return (u16)r;
}

// async global->LDS, 16B per lane. lds base must be wave-uniform; HW adds lane*16.
DEV void gl_lds16(const u16* g, u16* l) {
  __builtin_amdgcn_global_load_lds((const __attribute__((address_space(1))) u32*)g,
                                   (__attribute__((address_space(3))) u32*)l, 16, 0, 0);
}

// ---------------- cast fp32 -> bf16 (vectorized) ----------------
typedef u16 u16x4 __attribute__((ext_vector_type(4)));
__global__ __launch_bounds__(256) void cast_f32_bf16(const float* __restrict__ in,
                                                     u16* __restrict__ out, int n4) {
  int i = blockIdx.x * 256 + threadIdx.x;
  if (i >= n4) return;
  float4 v = ((const float4*)in)[i];
  u16x4 o;
  o.x = f2bf(v.x); o.y = f2bf(v.y); o.z = f2bf(v.z); o.w = f2bf(v.w);
  ((u16x4*)out)[i] = o;
}

// ---------------- transpose + cast: W (K,N) fp32 -> Wt (N,K) bf16 ----------------
__global__ __launch_bounds__(256) void transpose_cast(const float* __restrict__ W,
                                                      u16* __restrict__ Wt, int K, int N) {
  __shared__ float tile[64][65];
  int n0 = blockIdx.x * 64;
  int k0 = blockIdx.y * 64;
#pragma unroll
  for (int i = 0; i < 16; ++i) {
    int idx = threadIdx.x + i * 256;
    int r = idx >> 6, c = idx & 63;             // r: k-off, c: n-off
    tile[r][c] = W[(size_t)(k0 + r) * N + n0 + c];
  }
  __syncthreads();
#pragma unroll
  for (int i = 0; i < 16; ++i) {
    int idx = threadIdx.x + i * 256;
    int r = idx >> 6, c = idx & 63;             // r: n-off, c: k-off
    Wt[(size_t)(n0 + r) * K + k0 + c] = f2bf(tile[c][r]);
  }
}

// ---------------- transpose V: (B*L, 2048) bf16, cols h*128+dv -> Vt (B,H,128,L) ----------------
__global__ __launch_bounds__(256) void transpose_v(const u16* __restrict__ V,
                                                   u16* __restrict__ Vt) {
  __shared__ float tile[64][65];
  int l0 = blockIdx.x * 64;   // 32 tiles over L
  int d0 = blockIdx.y * 64;   // 2 tiles over 128
  int bh = blockIdx.z;        // b*16+h
  int b = bh >> 4, h = bh & 15;
#pragma unroll
  for (int i = 0; i < 16; ++i) {
    int idx = threadIdx.x + i * 256;
    int r = idx >> 6, c = idx & 63;
    tile[r][c] = bf2f(V[(size_t)(b * 2048 + l0 + r) * 2048 + h * 128 + d0 + c]);
  }
  __syncthreads();
#pragma unroll
  for (int i = 0; i < 16; ++i) {
    int idx = threadIdx.x + i * 256;
    int rr = idx >> 6, cc = idx & 63;  // rr: dv-off, cc: l-off
    Vt[((size_t)bh * 128 + d0 + rr) * 2048 + l0 + cc] = f2bf(tile[cc][rr]);
  }
}

// ---------------- GEMM: C(MxN) = A(MxK bf16) * Bt(NxK bf16)^T, m97 structure ----------------
DEV void gemm_store(float* C, size_t idx, float v) { C[idx] = v; }
DEV void gemm_store(u16* C, size_t idx, float v) { C[idx] = f2bf(v); }

template <typename OT>
__global__ __launch_bounds__(256) void gemm_bt(const u16* __restrict__ A,
                                               const u16* __restrict__ Bt,
                                               OT* __restrict__ C, int M, int N, int K) {
  __shared__ u16 As[128 * 32];
  __shared__ u16 Bs[128 * 32];
  const int tid = threadIdx.x;
  const int lane = tid & 63;
  const int w = tid >> 6;       // 0..3
  const int quad = lane >> 4;   // 0..3
  const int l15 = lane & 15;
  const int m0 = blockIdx.y * 128;
  const int n0 = blockIdx.x * 128;
  const int wm = (w & 1) * 64;
  const int wn = (w >> 1) * 64;

  f32x4 acc[4][4] = {};

  for (int k0 = 0; k0 < K; k0 += 32) {
#pragma unroll
    for (int it = 0; it < 2; ++it) {
      int ca = w * 128 + it * 64;       // wave-uniform base chunk
      int c = ca + lane;
      int row = c >> 2, kc = (c & 3) * 8;
      gl_lds16(A + (size_t)(m0 + row) * K + k0 + kc, &As[ca * 8]);
      gl_lds16(Bt + (size_t)(n0 + row) * K + k0 + kc, &Bs[ca * 8]);
    }
    __syncthreads();   // waits vmcnt(0) for global_load_lds
    bf16x8 af[4], bf[4];
#pragma unroll
    for (int mt = 0; mt < 4; ++mt) af[mt] = *(const bf16x8*)&As[(wm + mt * 16 + l15) * 32 + quad * 8];
#pragma unroll
    for (int nt = 0; nt < 4; ++nt) bf[nt] = *(const bf16x8*)&Bs[(wn + nt * 16 + l15) * 32 + quad * 8];
#pragma unroll
    for (int mt = 0; mt < 4; ++mt)
#pragma unroll
      for (int nt = 0; nt < 4; ++nt)
        acc[mt][nt] = __builtin_amdgcn_mfma_f32_16x16x32_bf16(af[mt], bf[nt], acc[mt][nt], 0, 0, 0);
    __syncthreads();
  }
#pragma unroll
  for (int mt = 0; mt < 4; ++mt)
#pragma unroll
    for (int nt = 0; nt < 4; ++nt) {
      int col = n0 + wn + nt * 16 + l15;
      if (col >= N) continue;   // only triggers for N=64 (W_KR)
#pragma unroll
      for (int r = 0; r < 4; ++r) {
        int rowg = m0 + wm + mt * 16 + quad * 4 + r;
        gemm_store(C, (size_t)rowg * N + col, acc[mt][nt][r]);
      }
    }
}

// ---------------- build q / k: rope + concat + L2-normalize, one wave per (token, head) ----------------
__global__ __launch_bounds__(256) void build_q(const u16* __restrict__ qc,
                                               const u16* __restrict__ qrr,
                                               const float* __restrict__ s_qk,
                                               u16* __restrict__ qn) {
  const int wid = blockIdx.x * 4 + (threadIdx.x >> 6);
  const int lane = threadIdx.x & 63;
  const int token = wid >> 4;     // b*L + l
  const int h = wid & 15;
  const int b = token >> 11;
  const int l = token & 2047;
  float v0 = bf2f(qc[(size_t)token * 2048 + h * 128 + lane]);
  float v1 = bf2f(qc[(size_t)token * 2048 + h * 128 + 64 + lane]);
  int j = lane & 31;
  float freq = powf(10000.f, -(float)j * (1.f / 32.f));
  float ang = (float)l * freq;
  float cs = cosf(ang), sn = sinf(ang);
  float xr = bf2f(qrr[(size_t)token * 1024 + h * 64 + lane]);
  float xo = bf2f(qrr[(size_t)token * 1024 + h * 64 + (lane ^ 32)]);
  float v2 = (lane < 32) ? (xr * cs - xo * sn) : (xr * cs + xo * sn);
  float ss = v0 * v0 + v1 * v1 + v2 * v2;
#pragma unroll
  for (int off = 1; off < 64; off <<= 1) ss += __shfl_xor(ss, off, 64);
  float scale = s_qk[0] / fmaxf(sqrtf(ss), 1e-12f);
  u16* out = qn + (((size_t)(b * 16 + h) * 2048) + l) * 192;
  out[lane] = f2bf(v0 * scale);
  out[64 + lane] = f2bf(v1 * scale);
  out[128 + lane] = f2bf(v2 * scale);
}

__global__ __launch_bounds__(256) void build_k(const u16* __restrict__ kc_,
                                               const u16* __restrict__ krr,
                                               u16* __restrict__ kn) {
  const int wid = blockIdx.x * 4 + (threadIdx.x >> 6);
  const int lane = threadIdx.x & 63;
  const int token = wid >> 4;
  const int h = wid & 15;
  const int b = token >> 11;
  const int l = token & 2047;
  float v0 = bf2f(kc_[(size_t)token * 2048 + h * 128 + lane]);
  float v1 = bf2f(kc_[(size_t)token * 2048 + h * 128 + 64 + lane]);
  int j = lane & 31;
  float freq = powf(10000.f, -(float)j * (1.f / 32.f));
  float ang = (float)l * freq;
  float cs = cosf(ang), sn = sinf(ang);
  float xr = bf2f(krr[(size_t)token * 64 + lane]);
  float xo = bf2f(krr[(size_t)token * 64 + (lane ^ 32)]);
  float v2 = (lane < 32) ? (xr * cs - xo * sn) : (xr * cs + xo * sn);
  float ss = v0 * v0 + v1 * v1 + v2 * v2;
#pragma unroll
  for (int off = 1; off < 64; off <<= 1) ss += __shfl_xor(ss, off, 64);
  float scale = 1.0f / fmaxf(sqrtf(ss), 1e-12f);
  u16* out = kn + (((size_t)(b * 16 + h) * 2048) + l) * 192;
  out[lane] = f2bf(v0 * scale);
  out[64 + lane] = f2bf(v1 * scale);
  out[128 + lane] = f2bf(v2 * scale);
}

// ---------------- flash attention (causal), 512 thr ----------------
// LDS 48KB -> 3 blocks/CU (24 waves). K/V staged via global_load_lds into
// XOR-swizzled dense layouts (bank-minimal b128 frag reads). P round-trip
// through a per-wave 16x32 buffer, one 32-key half at a time.
__global__ __launch_bounds__(512, 6) void flash_attn(const u16* __restrict__ Q,   // (B,H,L,192)
                                                     const u16* __restrict__ Kn,  // (B,H,L,192)
                                                     const u16* __restrict__ Vt,  // (B,H,128,L)
                                                     u16* __restrict__ O) {       // (B,L,2048)
  constexpr int L = 2048, DQK = 192, DV = 128;
  __shared__ u16 Ks[64 * 192];       // dense, 16B-chunk-swizzled: phys_c = c ^ (row&7)
  __shared__ u16 Vs[DV * 64];        // dense, swizzled likewise
  __shared__ u16 Ps[8 * 16 * 32];    // per-wave P staging (one 32-key half)
  const int tid = threadIdx.x;
  const int lane = tid & 63;
  const int w = tid >> 6;       // 0..7, q-row group
  const int quad = lane >> 4;
  const int l15 = lane & 15;
  const int qt = 15 - blockIdx.x;   // reversed: longest blocks dispatched first
  const int bh = blockIdx.y;        // b*16+h
  const int b = bh >> 4, h = bh & 15;

  const u16* Qg = Q + ((size_t)bh * L + qt * 128) * DQK;
  const u16* Kg = Kn + (size_t)bh * L * DQK;
  const u16* Vg = Vt + (size_t)bh * DV * L;

  // Q fragments in registers: wave w owns q rows w*16..w*16+15
  bf16x8 qf[6];
#pragma unroll
  for (int kd = 0; kd < 6; ++kd)
    qf[kd] = *(const bf16x8*)&Qg[(w * 16 + l15) * DQK + kd * 32 + quad * 8];

  f32x4 oacc[8] = {};
  float mrow[4], lrow[4];
#pragma unroll
  for (int r = 0; r < 4; ++r) { mrow[r] = -1e30f; lrow[r] = 0.f; }

  const int nkv = 2 * qt + 2;
  for (int kt = 0; kt < nkv; ++kt) {
    // stage K tile: 64 rows x 24 chunks(16B) = 1536 phys chunks; wave w covers [w*192, w*192+192)
#pragma unroll
    for (int it = 0; it < 3; ++it) {
      int pbase = w * 192 + it * 64;
      int p = pbase + lane;
      int r = p / 24, cp = p % 24;
      int c = cp ^ (r & 7);            // logical chunk this phys slot holds
      gl_lds16(Kg + (size_t)(kt * 64 + r) * DQK + c * 8, &Ks[pbase * 8]);
    }
    // stage V tile: 128 dv x 8 chunks = 1024 phys chunks; wave w covers [w*128, w*128+128)
#pragma unroll
    for (int it = 0; it < 2; ++it) {
      int pbase = w * 128 + it * 64;
      int p = pbase + lane;
      int dv = p >> 3, cp = p & 7;
      int c = cp ^ (dv & 7);
      gl_lds16(Vg + (size_t)dv * L + kt * 64 + c * 8, &Vs[pbase * 8]);
    }
    __syncthreads();   // drains vmcnt(0)

    // S (16q x 64k) per wave
    f32x4 s[4] = {};
#pragma unroll
    for (int kd = 0; kd < 6; ++kd) {
      bf16x8 a = qf[kd];
#pragma unroll
      for (int nt = 0; nt < 4; ++nt) {
        int row = nt * 16 + l15;
        int cp = (kd * 4 + quad) ^ (l15 & 7);
        bf16x8 bb = *(const bf16x8*)&Ks[row * DQK + cp * 8];
        s[nt] = __builtin_amdgcn_mfma_f32_16x16x32_bf16(a, bb, s[nt], 0, 0, 0);
      }
    }

    // causal mask + online softmax (rows quad*4+r, cols l15+16*nt)
    const int qrow_base = qt * 128 + w * 16 + quad * 4;
    const int kcol = kt * 64 + l15;
    float pv[4][4];  // [nt][r]
#pragma unroll
    for (int r = 0; r < 4; ++r) {
      float mx = -1e30f;
#pragma unroll
      for (int nt = 0; nt < 4; ++nt) {
        float sv = s[nt][r];
        if (kcol + nt * 16 > qrow_base + r) sv = -1e30f;
        s[nt][r] = sv;
        mx = fmaxf(mx, sv);
      }
#pragma unroll
      for (int off = 1; off < 16; off <<= 1) mx = fmaxf(mx, __shfl_xor(mx, off, 64));
      float mnew = fmaxf(mrow[r], mx);
      float alpha = __expf(mrow[r] - mnew);
      float rs = 0.f;
#pragma unroll
      for (int nt = 0; nt < 4; ++nt) {
        float p = __expf(s[nt][r] - mnew);
        pv[nt][r] = p;
        rs += p;
      }
#pragma unroll
      for (int off = 1; off < 16; off <<= 1) rs += __shfl_xor(rs, off, 64);
      lrow[r] = lrow[r] * alpha + rs;
      mrow[r] = mnew;
#pragma unroll
      for (int nt2 = 0; nt2 < 8; ++nt2) oacc[nt2][r] *= alpha;
    }

    // P -> per-wave LDS (C-layout scatter) -> A-layout read, one 32-key half at a time
    u16* Pw = &Ps[w * 512];
#pragma unroll
    for (int kk = 0; kk < 2; ++kk) {
#pragma unroll
      for (int ntl = 0; ntl < 2; ++ntl)
#pragma unroll
        for (int r = 0; r < 4; ++r)
          Pw[(quad * 4 + r) * 32 + ntl * 16 + l15] = f2bf(pv[kk * 2 + ntl][r]);
      asm volatile("s_waitcnt lgkmcnt(0)" ::: "memory");  // within-wave WAR/RAW order
      bf16x8 p = *(const bf16x8*)&Pw[l15 * 32 + quad * 8];
#pragma unroll
      for (int nt2 = 0; nt2 < 8; ++nt2) {
        int dv = nt2 * 16 + l15;
        int cp = (kk * 4 + quad) ^ (l15 & 7);
        bf16x8 vv = *(const bf16x8*)&Vs[dv * 64 + cp * 8];
        oacc[nt2] = __builtin_amdgcn_mfma_f32_16x16x32_bf16(p, vv, oacc[nt2], 0, 0, 0);
      }
    }
    __syncthreads();  // before restaging Ks/Vs
  }

  // final: divide by l, store O (B,L,2048) bf16
#pragma unroll
  for (int nt2 = 0; nt2 < 8; ++nt2)
#pragma unroll
    for (int r = 0; r < 4; ++r) {
      int lg = qt * 128 + w * 16 + quad * 4 + r;
      float ov = oacc[nt2][r] / lrow[r];
      O[((size_t)b * L + lg) * 2048 + h * 128 + nt2 * 16 + l15] = f2bf(ov);
    }
}

// ---------------- launcher ----------------
extern "C" void kernel_launch(void* const* d_in, const int* in_sizes, int n_in,
                              void* d_out, int out_size, void* d_ws, size_t ws_size,
                              hipStream_t stream) {
  const float* x     = (const float*)d_in[0];
  const float* W_DKV = (const float*)d_in[1];
  const float* W_UK  = (const float*)d_in[2];
  const float* W_UV  = (const float*)d_in[3];
  const float* W_DQ  = (const float*)d_in[4];
  const float* W_UQ  = (const float*)d_in[5];
  const float* W_QR  = (const float*)d_in[6];
  const float* W_KR  = (const float*)d_in[7];
  const float* W_O   = (const float*)d_in[8];
  const float* s_qk  = (const float*)d_in[9];

  char* p = (char*)d_ws;
  auto alloc = [&](size_t bytes) {
    char* r = p;
    p += (bytes + 255) & ~(size_t)255;
    return r;
  };
  u16* xb    = (u16*)alloc((size_t)8192 * 2048 * 2);   // region start (later reused by qn)
  u16* WtDKV = (u16*)alloc((size_t)1024 * 2048 * 2);
  u16* WtUK  = (u16*)alloc((size_t)2048 * 1024 * 2);
  u16* WtUV  = (u16*)alloc((size_t)2048 * 1024 * 2);
  u16* WtDQ  = (u16*)alloc((size_t)1024 * 2048 * 2);
  u16* WtUQ  = (u16*)alloc((size_t)2048 * 1024 * 2);
  u16* WtQR  = (u16*)alloc((size_t)1024 * 1024 * 2);
  u16* WtKR  = (u16*)alloc((size_t)128 * 2048 * 2);    // padded 64->128 rows (GEMM over-read)
  u16* WtO   = (u16*)alloc((size_t)2048 * 2048 * 2);
  u16* ckv   = (u16*)alloc((size_t)8192 * 1024 * 2);
  u16* cq    = (u16*)alloc((size_t)8192 * 1024 * 2);
  u16* kc    = (u16*)alloc((size_t)8192 * 2048 * 2);   // later reused as Vt
  u16* vb    = (u16*)alloc((size_t)8192 * 2048 * 2);
  u16* qc    = (u16*)alloc((size_t)8192 * 2048 * 2);   // later reused as O
  u16* qr    = (u16*)alloc((size_t)8192 * 1024 * 2);
  u16* kr    = (u16*)alloc((size_t)8192 * 64 * 2);
  u16* kn    = (u16*)alloc((size_t)64 * 2048 * 192 * 2);
  // aliases (all writers run strictly after the aliased buffer's last reader):
  u16* qn = (u16*)d_ws;  // 50,331,648 B == xb+WtDKV+WtUK+WtUV+WtDQ exactly; all dead before build_q
  u16* Vt = kc;          // kc dead after build_k
  u16* O  = qc;          // qc dead after build_q

  // 1) casts / weight transposes
  cast_f32_bf16<<<16384, 256, 0, stream>>>(x, xb, 8192 * 2048 / 4);
  transpose_cast<<<dim3(16, 32), 256, 0, stream>>>(W_DKV, WtDKV, 2048, 1024);
  transpose_cast<<<dim3(32, 16), 256, 0, stream>>>(W_UK,  WtUK,  1024, 2048);
  transpose_cast<<<dim3(32, 16), 256, 0, stream>>>(W_UV,  WtUV,  1024, 2048);
  transpose_cast<<<dim3(16, 32), 256, 0, stream>>>(W_DQ,  WtDQ,  2048, 1024);
  transpose_cast<<<dim3(32, 16), 256, 0, stream>>>(W_UQ,  WtUQ,  1024, 2048);
  transpose_cast<<<dim3(16, 16), 256, 0, stream>>>(W_QR,  WtQR,  1024, 1024);
  transpose_cast<<<dim3(1, 32),  256, 0, stream>>>(W_KR,  WtKR,  2048, 64);
  transpose_cast<<<dim3(32, 32), 256, 0, stream>>>(W_O,   WtO,   2048, 2048);

  // 2) projection GEMMs
  gemm_bt<u16><<<dim3(8, 64),  256, 0, stream>>>(xb,  WtDKV, ckv, 8192, 1024, 2048);
  gemm_bt<u16><<<dim3(8, 64),  256, 0, stream>>>(xb,  WtDQ,  cq,  8192, 1024, 2048);
  gemm_bt<u16><<<dim3(16, 64), 256, 0, stream>>>(ckv, WtUK,  kc,  8192, 2048, 1024);
  gemm_bt<u16><<<dim3(16, 64), 256, 0, stream>>>(ckv, WtUV,  vb,  8192, 2048, 1024);
  gemm_bt<u16><<<dim3(16, 64), 256, 0, stream>>>(cq,  WtUQ,  qc,  8192, 2048, 1024);
  gemm_bt<u16><<<dim3(8, 64),  256, 0, stream>>>(cq,  WtQR,  qr,  8192, 1024, 1024);
  gemm_bt<u16><<<dim3(1, 64),  256, 0, stream>>>(xb,  WtKR,  kr,  8192, 64,   2048);

  // 3) rope + concat + normalize
  build_q<<<32768, 256, 0, stream>>>(qc, qr, s_qk, qn);
  build_k<<<32768, 256, 0, stream>>>(kc, kr, kn);

  // 4) V transpose (writes over kc region — kc consumed above)
  transpose_v<<<dim3(32, 2, 64), 256, 0, stream>>>(vb, Vt);

  // 5) attention (writes over qc region — qc consumed above)
  flash_attn<<<dim3(16, 64), 512, 0, stream>>>(qn, kn, Vt, O);

  // 6) output projection -> fp32 d_out
  gemm_bt<float><<<dim3(16, 64), 256, 0, stream>>>(O, WtO, (float*)d_out, 8192, 2048, 2048);
}

// Round 4
// 1280.933 us; speedup vs baseline: 1.2017x; 1.2017x over previous
//
#include <hip/hip_runtime.h>
#include <stdint.h>

typedef unsigned short u16;
typedef unsigned int u32;
typedef short bf16x8 __attribute__((ext_vector_type(8)));
typedef float f32x4 __attribute__((ext_vector_type(4)));

#define DEV __device__ __forceinline__

DEV float bf2f(u16 u) { union { float f; u32 i; } x; x.i = ((u32)u) << 16; return x.f; }
DEV u16 f2bf(float f) {
  union { float f; u32 i; } x; x.f = f;
  u32 i = x.i;
  u32 r = (i + 0x7fffu + ((i >> 16) & 1u)) >> 16;  // RTNE
  return (u16)r;
}

// async global->LDS, 16B per lane. lds base must be wave-uniform; HW adds lane*16.
DEV void gl_lds16(const u16* g, u16* l) {
  __builtin_amdgcn_global_load_lds((const __attribute__((address_space(1))) u32*)g,
                                   (__attribute__((address_space(3))) u32*)l, 16, 0, 0);
}

// ---------------- cast fp32 -> bf16 (vectorized) ----------------
typedef u16 u16x4 __attribute__((ext_vector_type(4)));
__global__ __launch_bounds__(256) void cast_f32_bf16(const float* __restrict__ in,
                                                     u16* __restrict__ out, int n4) {
  int i = blockIdx.x * 256 + threadIdx.x;
  if (i >= n4) return;
  float4 v = ((const float4*)in)[i];
  u16x4 o;
  o.x = f2bf(v.x); o.y = f2bf(v.y); o.z = f2bf(v.z); o.w = f2bf(v.w);
  ((u16x4*)out)[i] = o;
}

// ---------------- transpose + cast: W (K,N) fp32 -> Wt (N,K) bf16 ----------------
__global__ __launch_bounds__(256) void transpose_cast(const float* __restrict__ W,
                                                      u16* __restrict__ Wt, int K, int N) {
  __shared__ float tile[64][65];
  int n0 = blockIdx.x * 64;
  int k0 = blockIdx.y * 64;
#pragma unroll
  for (int i = 0; i < 16; ++i) {
    int idx = threadIdx.x + i * 256;
    int r = idx >> 6, c = idx & 63;             // r: k-off, c: n-off
    tile[r][c] = W[(size_t)(k0 + r) * N + n0 + c];
  }
  __syncthreads();
#pragma unroll
  for (int i = 0; i < 16; ++i) {
    int idx = threadIdx.x + i * 256;
    int r = idx >> 6, c = idx & 63;             // r: n-off, c: k-off
    Wt[(size_t)(n0 + r) * K + k0 + c] = f2bf(tile[c][r]);
  }
}

// ---------------- transpose V: rows of kcv (B*L, 4096), v = cols 2048+h*128+dv -> Vt (B,H,128,L) ----------------
__global__ __launch_bounds__(256) void transpose_v(const u16* __restrict__ KCV,
                                                   u16* __restrict__ Vt) {
  __shared__ float tile[64][65];
  int l0 = blockIdx.x * 64;   // 32 tiles over L
  int d0 = blockIdx.y * 64;   // 2 tiles over 128
  int bh = blockIdx.z;        // b*16+h
  int b = bh >> 4, h = bh & 15;
#pragma unroll
  for (int i = 0; i < 16; ++i) {
    int idx = threadIdx.x + i * 256;
    int r = idx >> 6, c = idx & 63;
    tile[r][c] = bf2f(KCV[(size_t)(b * 2048 + l0 + r) * 4096 + 2048 + h * 128 + d0 + c]);
  }
  __syncthreads();
#pragma unroll
  for (int i = 0; i < 16; ++i) {
    int idx = threadIdx.x + i * 256;
    int rr = idx >> 6, cc = idx & 63;  // rr: dv-off, cc: l-off
    Vt[((size_t)bh * 128 + d0 + rr) * 2048 + l0 + cc] = f2bf(tile[cc][rr]);
  }
}

// ---------------- GEMM: C(MxN) = A(MxK bf16, row-stride lda) * Bt(NxK bf16)^T ----------------
DEV void gemm_store(float* C, size_t idx, float v) { C[idx] = v; }
DEV void gemm_store(u16* C, size_t idx, float v) { C[idx] = f2bf(v); }

template <typename OT>
__global__ __launch_bounds__(256) void gemm_bt(const u16* __restrict__ A, int lda,
                                               const u16* __restrict__ Bt,
                                               OT* __restrict__ C, int ldc,
                                               int M, int N, int K) {
  __shared__ u16 As[128 * 32];
  __shared__ u16 Bs[128 * 32];
  const int tid = threadIdx.x;
  const int lane = tid & 63;
  const int w = tid >> 6;       // 0..3
  const int quad = lane >> 4;   // 0..3
  const int l15 = lane & 15;
  const int m0 = blockIdx.y * 128;
  const int n0 = blockIdx.x * 128;
  const int wm = (w & 1) * 64;
  const int wn = (w >> 1) * 64;

  f32x4 acc[4][4] = {};

  for (int k0 = 0; k0 < K; k0 += 32) {
#pragma unroll
    for (int it = 0; it < 2; ++it) {
      int ca = w * 128 + it * 64;       // wave-uniform base chunk
      int c = ca + lane;
      int row = c >> 2, kc = (c & 3) * 8;
      gl_lds16(A + (size_t)(m0 + row) * lda + k0 + kc, &As[ca * 8]);
      gl_lds16(Bt + (size_t)(n0 + row) * K + k0 + kc, &Bs[ca * 8]);
    }
    __syncthreads();   // waits vmcnt(0) for global_load_lds
    bf16x8 af[4], bf[4];
#pragma unroll
    for (int mt = 0; mt < 4; ++mt) af[mt] = *(const bf16x8*)&As[(wm + mt * 16 + l15) * 32 + quad * 8];
#pragma unroll
    for (int nt = 0; nt < 4; ++nt) bf[nt] = *(const bf16x8*)&Bs[(wn + nt * 16 + l15) * 32 + quad * 8];
#pragma unroll
    for (int mt = 0; mt < 4; ++mt)
#pragma unroll
      for (int nt = 0; nt < 4; ++nt)
        acc[mt][nt] = __builtin_amdgcn_mfma_f32_16x16x32_bf16(af[mt], bf[nt], acc[mt][nt], 0, 0, 0);
    __syncthreads();
  }
#pragma unroll
  for (int mt = 0; mt < 4; ++mt)
#pragma unroll
    for (int nt = 0; nt < 4; ++nt) {
      int col = n0 + wn + nt * 16 + l15;
      if (col >= N) continue;   // only triggers for N=64 (W_KR)
#pragma unroll
      for (int r = 0; r < 4; ++r) {
        int rowg = m0 + wm + mt * 16 + quad * 4 + r;
        gemm_store(C, (size_t)rowg * ldc + col, acc[mt][nt][r]);
      }
    }
}

// ---------------- build q / k: rope + concat + L2-normalize, one wave per (token, head) ----------------
__global__ __launch_bounds__(256) void build_q(const u16* __restrict__ qcr,  // (B*L, 3072): qc|qr
                                               const float* __restrict__ s_qk,
                                               u16* __restrict__ qn) {
  const int wid = blockIdx.x * 4 + (threadIdx.x >> 6);
  const int lane = threadIdx.x & 63;
  const int token = wid >> 4;     // b*L + l
  const int h = wid & 15;
  const int b = token >> 11;
  const int l = token & 2047;
  float v0 = bf2f(qcr[(size_t)token * 3072 + h * 128 + lane]);
  float v1 = bf2f(qcr[(size_t)token * 3072 + h * 128 + 64 + lane]);
  int j = lane & 31;
  float freq = powf(10000.f, -(float)j * (1.f / 32.f));
  float ang = (float)l * freq;
  float cs = cosf(ang), sn = sinf(ang);
  float xr = bf2f(qcr[(size_t)token * 3072 + 2048 + h * 64 + lane]);
  float xo = bf2f(qcr[(size_t)token * 3072 + 2048 + h * 64 + (lane ^ 32)]);
  float v2 = (lane < 32) ? (xr * cs - xo * sn) : (xr * cs + xo * sn);
  float ss = v0 * v0 + v1 * v1 + v2 * v2;
#pragma unroll
  for (int off = 1; off < 64; off <<= 1) ss += __shfl_xor(ss, off, 64);
  float scale = s_qk[0] / fmaxf(sqrtf(ss), 1e-12f);
  u16* out = qn + (((size_t)(b * 16 + h) * 2048) + l) * 192;
  out[lane] = f2bf(v0 * scale);
  out[64 + lane] = f2bf(v1 * scale);
  out[128 + lane] = f2bf(v2 * scale);
}

__global__ __launch_bounds__(256) void build_k(const u16* __restrict__ kcv,  // (B*L, 4096): kc|v
                                               const u16* __restrict__ krr,  // (B*L, 64)
                                               u16* __restrict__ kn) {
  const int wid = blockIdx.x * 4 + (threadIdx.x >> 6);
  const int lane = threadIdx.x & 63;
  const int token = wid >> 4;
  const int h = wid & 15;
  const int b = token >> 11;
  const int l = token & 2047;
  float v0 = bf2f(kcv[(size_t)token * 4096 + h * 128 + lane]);
  float v1 = bf2f(kcv[(size_t)token * 4096 + h * 128 + 64 + lane]);
  int j = lane & 31;
  float freq = powf(10000.f, -(float)j * (1.f / 32.f));
  float ang = (float)l * freq;
  float cs = cosf(ang), sn = sinf(ang);
  float xr = bf2f(krr[(size_t)token * 64 + lane]);
  float xo = bf2f(krr[(size_t)token * 64 + (lane ^ 32)]);
  float v2 = (lane < 32) ? (xr * cs - xo * sn) : (xr * cs + xo * sn);
  float ss = v0 * v0 + v1 * v1 + v2 * v2;
#pragma unroll
  for (int off = 1; off < 64; off <<= 1) ss += __shfl_xor(ss, off, 64);
  float scale = 1.0f / fmaxf(sqrtf(ss), 1e-12f);
  u16* out = kn + (((size_t)(b * 16 + h) * 2048) + l) * 192;
  out[lane] = f2bf(v0 * scale);
  out[64 + lane] = f2bf(v1 * scale);
  out[128 + lane] = f2bf(v2 * scale);
}

// ---------------- flash attention (causal), 512 thr ----------------
// XCD-clustered: all 16 qt-blocks of one bh land on one XCD (lin%8 heuristic)
// so the 1.3MB K+V stream stays L2-resident. LDS ~50KB -> 3 blocks/CU.
__global__ __launch_bounds__(512, 6) void flash_attn(const u16* __restrict__ Q,   // (B,H,L,192)
                                                     const u16* __restrict__ Kn,  // (B,H,L,192)
                                                     const u16* __restrict__ Vt,  // (B,H,128,L)
                                                     u16* __restrict__ O) {       // (B,L,2048)
  constexpr int L = 2048, DQK = 192, DV = 128;
  constexpr int PSTR = 36;           // Ps row stride (u16): 32-bank-clean scatter
  __shared__ u16 Ks[64 * 192];       // dense, 16B-chunk-swizzled: phys_c = c ^ (row&7)
  __shared__ u16 Vs[DV * 64];        // dense, swizzled likewise
  __shared__ u16 Ps[8 * 16 * PSTR];  // per-wave P staging (one 32-key half)
  const int tid = threadIdx.x;
  const int lane = tid & 63;
  const int w = tid >> 6;       // 0..7, q-row group
  const int quad = lane >> 4;
  const int l15 = lane & 15;
  // block mapping: lin = g*8 + xcd; bh = (g>>4)*8 + xcd; qt = 15-(g&15)
  const int lin = blockIdx.x;
  const int xcd = lin & 7;
  const int g = lin >> 3;
  const int bh = ((g >> 4) << 3) | xcd;
  const int qt = 15 - (g & 15);
  const int b = bh >> 4, h = bh & 15;

  const u16* Qg = Q + ((size_t)bh * L + qt * 128) * DQK;
  const u16* Kg = Kn + (size_t)bh * L * DQK;
  const u16* Vg = Vt + (size_t)bh * DV * L;

  // Q fragments in registers: wave w owns q rows w*16..w*16+15
  bf16x8 qf[6];
#pragma unroll
  for (int kd = 0; kd < 6; ++kd)
    qf[kd] = *(const bf16x8*)&Qg[(w * 16 + l15) * DQK + kd * 32 + quad * 8];

  f32x4 oacc[8] = {};
  float mrow[4], lrow[4];
#pragma unroll
  for (int r = 0; r < 4; ++r) { mrow[r] = -1e30f; lrow[r] = 0.f; }

  const int nkv = 2 * qt + 2;
  for (int kt = 0; kt < nkv; ++kt) {
    // stage K tile: 64 rows x 24 chunks(16B) = 1536 phys chunks; wave w covers [w*192, w*192+192)
#pragma unroll
    for (int it = 0; it < 3; ++it) {
      int pbase = w * 192 + it * 64;
      int p = pbase + lane;
      int r = p / 24, cp = p % 24;
      int c = cp ^ (r & 7);            // logical chunk this phys slot holds
      gl_lds16(Kg + (size_t)(kt * 64 + r) * DQK + c * 8, &Ks[pbase * 8]);
    }
    // stage V tile: 128 dv x 8 chunks = 1024 phys chunks; wave w covers [w*128, w*128+128)
#pragma unroll
    for (int it = 0; it < 2; ++it) {
      int pbase = w * 128 + it * 64;
      int p = pbase + lane;
      int dv = p >> 3, cp = p & 7;
      int c = cp ^ (dv & 7);
      gl_lds16(Vg + (size_t)dv * L + kt * 64 + c * 8, &Vs[pbase * 8]);
    }
    __syncthreads();   // drains vmcnt(0)

    // S (16q x 64k) per wave
    f32x4 s[4] = {};
#pragma unroll
    for (int kd = 0; kd < 6; ++kd) {
      bf16x8 a = qf[kd];
#pragma unroll
      for (int nt = 0; nt < 4; ++nt) {
        int row = nt * 16 + l15;
        int cp = (kd * 4 + quad) ^ (l15 & 7);
        bf16x8 bb = *(const bf16x8*)&Ks[row * DQK + cp * 8];
        s[nt] = __builtin_amdgcn_mfma_f32_16x16x32_bf16(a, bb, s[nt], 0, 0, 0);
      }
    }

    // causal mask + online softmax (rows quad*4+r, cols l15+16*nt)
    const int qrow_base = qt * 128 + w * 16 + quad * 4;
    const int kcol = kt * 64 + l15;
    float pv[4][4];  // [nt][r]
#pragma unroll
    for (int r = 0; r < 4; ++r) {
      float mx = -1e30f;
#pragma unroll
      for (int nt = 0; nt < 4; ++nt) {
        float sv = s[nt][r];
        if (kcol + nt * 16 > qrow_base + r) sv = -1e30f;
        s[nt][r] = sv;
        mx = fmaxf(mx, sv);
      }
#pragma unroll
      for (int off = 1; off < 16; off <<= 1) mx = fmaxf(mx, __shfl_xor(mx, off, 64));
      float mnew = fmaxf(mrow[r], mx);
      float alpha = __expf(mrow[r] - mnew);
      float rs = 0.f;
#pragma unroll
      for (int nt = 0; nt < 4; ++nt) {
        float p = __expf(s[nt][r] - mnew);
        pv[nt][r] = p;
        rs += p;
      }
#pragma unroll
      for (int off = 1; off < 16; off <<= 1) rs += __shfl_xor(rs, off, 64);
      lrow[r] = lrow[r] * alpha + rs;
      mrow[r] = mnew;
#pragma unroll
      for (int nt2 = 0; nt2 < 8; ++nt2) oacc[nt2][r] *= alpha;
    }

    // P -> per-wave LDS (C-layout scatter) -> A-layout read, one 32-key half at a time
    u16* Pw = &Ps[w * 16 * PSTR];
#pragma unroll
    for (int kk = 0; kk < 2; ++kk) {
#pragma unroll
      for (int ntl = 0; ntl < 2; ++ntl)
#pragma unroll
        for (int r = 0; r < 4; ++r)
          Pw[(quad * 4 + r) * PSTR + ntl * 16 + l15] = f2bf(pv[kk * 2 + ntl][r]);
      asm volatile("s_waitcnt lgkmcnt(0)" ::: "memory");  // within-wave WAR/RAW order
      bf16x8 p = *(const bf16x8*)&Pw[l15 * PSTR + quad * 8];
#pragma unroll
      for (int nt2 = 0; nt2 < 8; ++nt2) {
        int dv = nt2 * 16 + l15;
        int cp = (kk * 4 + quad) ^ (l15 & 7);
        bf16x8 vv = *(const bf16x8*)&Vs[dv * 64 + cp * 8];
        oacc[nt2] = __builtin_amdgcn_mfma_f32_16x16x32_bf16(p, vv, oacc[nt2], 0, 0, 0);
      }
    }
    __syncthreads();  // before restaging Ks/Vs
  }

  // final: divide by l, store O (B,L,2048) bf16
#pragma unroll
  for (int nt2 = 0; nt2 < 8; ++nt2)
#pragma unroll
    for (int r = 0; r < 4; ++r) {
      int lg = qt * 128 + w * 16 + quad * 4 + r;
      float ov = oacc[nt2][r] / lrow[r];
      O[((size_t)b * L + lg) * 2048 + h * 128 + nt2 * 16 + l15] = f2bf(ov);
    }
}

// ---------------- launcher ----------------
extern "C" void kernel_launch(void* const* d_in, const int* in_sizes, int n_in,
                              void* d_out, int out_size, void* d_ws, size_t ws_size,
                              hipStream_t stream) {
  const float* x     = (const float*)d_in[0];
  const float* W_DKV = (const float*)d_in[1];
  const float* W_UK  = (const float*)d_in[2];
  const float* W_UV  = (const float*)d_in[3];
  const float* W_DQ  = (const float*)d_in[4];
  const float* W_UQ  = (const float*)d_in[5];
  const float* W_QR  = (const float*)d_in[6];
  const float* W_KR  = (const float*)d_in[7];
  const float* W_O   = (const float*)d_in[8];
  const float* s_qk  = (const float*)d_in[9];

  char* base = (char*)d_ws;
  // static layout (bytes) — high-water mark 232,259,584 B (221.5 MiB), proven budget 263.7 MB:
  u16* xb     = (u16*)(base);                        // [0, 33,554,432)           dead after G_KR
  u16* WtDKVQ = (u16*)(base + (size_t)33554432);     // [.., 41,943,040)  8.39 MB dead after G1
  u16* WtUKV  = (u16*)(base + (size_t)41943040);     // [.., 58,720,256) 16.78 MB dead after G2
  u16* WtUQR  = (u16*)(base + (size_t)58720256);     // [.., 71,303,168) 12.58 MB dead after G3
  u16* WtKR   = (u16*)(base + (size_t)71303168);     // [.., 71,827,456)  0.52 MB dead after G_KR
  u16* WtO    = (u16*)(base + (size_t)71827456);     // [.., 80,216,064)  8.39 MB live to end
  u16* ckvq   = (u16*)(base + (size_t)80216064);     // [.., 113,770,496) 33.55 MB dead after G3
  u16* kcv    = (u16*)(base + (size_t)113770496);    // [.., 180,879,360) 67.11 MB dead after transpose_v
  u16* qcr    = (u16*)(base + (size_t)180879360);    // [.., 231,211,008) 50.33 MB dead after build_q
  u16* kr     = (u16*)(base + (size_t)231211008);    // [.., 232,259,584)  1.05 MB
  // aliases (each writer runs strictly after the aliased region's last reader):
  u16* qn = (u16*)(base);      // 50.33 MB over xb+WtDKVQ+WtUKV (all dead before build_q)
  u16* kn = qcr;               // 50.33 MB, exact size match; build_k runs after build_q
  u16* Vt = ckvq;              // 33.55 MB over ckvq (dead after G3)
  u16* O  = kcv;               // 33.55 MB over kcv head (dead after transpose_v)

  // 1) casts / weight transposes (into merged layouts)
  cast_f32_bf16<<<16384, 256, 0, stream>>>(x, xb, 8192 * 2048 / 4);
  transpose_cast<<<dim3(16, 32), 256, 0, stream>>>(W_DKV, WtDKVQ,                  2048, 1024);
  transpose_cast<<<dim3(16, 32), 256, 0, stream>>>(W_DQ,  WtDKVQ + 1024 * 2048,    2048, 1024);
  transpose_cast<<<dim3(32, 16), 256, 0, stream>>>(W_UK,  WtUKV,                   1024, 2048);
  transpose_cast<<<dim3(32, 16), 256, 0, stream>>>(W_UV,  WtUKV + 2048 * 1024,     1024, 2048);
  transpose_cast<<<dim3(32, 16), 256, 0, stream>>>(W_UQ,  WtUQR,                   1024, 2048);
  transpose_cast<<<dim3(16, 16), 256, 0, stream>>>(W_QR,  WtUQR + 2048 * 1024,     1024, 1024);
  transpose_cast<<<dim3(1, 32),  256, 0, stream>>>(W_KR,  WtKR,                    2048, 64);
  transpose_cast<<<dim3(32, 32), 256, 0, stream>>>(W_O,   WtO,                     2048, 2048);

  // 2) merged projection GEMMs
  // G1: ckvq(8192x2048) = xb @ [W_DKV|W_DQ]
  gemm_bt<u16><<<dim3(16, 64), 256, 0, stream>>>(xb, 2048, WtDKVQ, ckvq, 2048, 8192, 2048, 2048);
  // G_KR: kr(8192x64) = xb @ W_KR   (xb dead after)
  gemm_bt<u16><<<dim3(1, 64),  256, 0, stream>>>(xb, 2048, WtKR, kr, 64, 8192, 64, 2048);
  // G2: kcv(8192x4096) = c_kv @ [W_UK|W_UV]
  gemm_bt<u16><<<dim3(32, 64), 256, 0, stream>>>(ckvq, 2048, WtUKV, kcv, 4096, 8192, 4096, 1024);
  // G3: qcr(8192x3072) = c_q @ [W_UQ|W_QR]   (ckvq dead after)
  gemm_bt<u16><<<dim3(24, 64), 256, 0, stream>>>(ckvq + 1024, 2048, WtUQR, qcr, 3072, 8192, 3072, 1024);

  // 3) rope + concat + normalize.  ORDER MATTERS: build_q consumes qcr, then
  //    build_k writes kn over the qcr region.
  build_q<<<32768, 256, 0, stream>>>(qcr, s_qk, qn);
  build_k<<<32768, 256, 0, stream>>>(kcv, kr, kn);

  // 4) V transpose (Vt over dead ckvq region)
  transpose_v<<<dim3(32, 2, 64), 256, 0, stream>>>(kcv, Vt);

  // 5) attention (O over dead kcv head)
  flash_attn<<<dim3(1024), 512, 0, stream>>>(qn, kn, Vt, O);

  // 6) output projection -> fp32 d_out
  gemm_bt<float><<<dim3(16, 64), 256, 0, stream>>>(O, 2048, WtO, (float*)d_out, 2048, 8192, 2048, 2048);
}

// Round 5
// 1279.952 us; speedup vs baseline: 1.2026x; 1.0008x over previous
//
#include <hip/hip_runtime.h>
#include <stdint.h>

typedef unsigned short u16;
typedef unsigned int u32;
typedef short bf16x8 __attribute__((ext_vector_type(8)));
typedef float f32x4 __attribute__((ext_vector_type(4)));
typedef u16 u16x4 __attribute__((ext_vector_type(4)));

#define DEV __device__ __forceinline__

DEV float bf2f(u16 u) { union { float f; u32 i; } x; x.i = ((u32)u) << 16; return x.f; }
DEV u16 f2bf(float f) {
  union { float f; u32 i; } x; x.f = f;
  u32 i = x.i;
  u32 r = (i + 0x7fffu + ((i >> 16) & 1u)) >> 16;  // RTNE
  return (u16)r;
}

// async global->LDS, 16B per lane. lds base must be wave-uniform; HW adds lane*16.
DEV void gl_lds16(const u16* g, u16* l) {
  __builtin_amdgcn_global_load_lds((const __attribute__((address_space(1))) u32*)g,
                                   (__attribute__((address_space(3))) u32*)l, 16, 0, 0);
}

// ---------------- cast fp32 -> bf16 (vectorized) ----------------
__global__ __launch_bounds__(256) void cast_f32_bf16(const float* __restrict__ in,
                                                     u16* __restrict__ out, int n4) {
  int i = blockIdx.x * 256 + threadIdx.x;
  if (i >= n4) return;
  float4 v = ((const float4*)in)[i];
  u16x4 o;
  o.x = f2bf(v.x); o.y = f2bf(v.y); o.z = f2bf(v.z); o.w = f2bf(v.w);
  ((u16x4*)out)[i] = o;
}

// ---------------- transpose + cast: W (K,N) fp32 -> Wt (N,K) bf16 ----------------
__global__ __launch_bounds__(256) void transpose_cast(const float* __restrict__ W,
                                                      u16* __restrict__ Wt, int K, int N) {
  __shared__ float tile[64][65];
  int n0 = blockIdx.x * 64;
  int k0 = blockIdx.y * 64;
#pragma unroll
  for (int i = 0; i < 16; ++i) {
    int idx = threadIdx.x + i * 256;
    int r = idx >> 6, c = idx & 63;             // r: k-off, c: n-off
    tile[r][c] = W[(size_t)(k0 + r) * N + n0 + c];
  }
  __syncthreads();
#pragma unroll
  for (int i = 0; i < 16; ++i) {
    int idx = threadIdx.x + i * 256;
    int r = idx >> 6, c = idx & 63;             // r: n-off, c: k-off
    Wt[(size_t)(n0 + r) * K + k0 + c] = f2bf(tile[c][r]);
  }
}

// ---------------- transpose V: rows of kcv (B*L, 4096), v = cols 2048+h*128+dv -> Vt (B,H,128,L) ----------------
__global__ __launch_bounds__(256) void transpose_v(const u16* __restrict__ KCV,
                                                   u16* __restrict__ Vt) {
  __shared__ float tile[64][65];
  int l0 = blockIdx.x * 64;   // 32 tiles over L
  int d0 = blockIdx.y * 64;   // 2 tiles over 128
  int bh = blockIdx.z;        // b*16+h
  int b = bh >> 4, h = bh & 15;
#pragma unroll
  for (int i = 0; i < 16; ++i) {
    int idx = threadIdx.x + i * 256;
    int r = idx >> 6, c = idx & 63;
    tile[r][c] = bf2f(KCV[(size_t)(b * 2048 + l0 + r) * 4096 + 2048 + h * 128 + d0 + c]);
  }
  __syncthreads();
#pragma unroll
  for (int i = 0; i < 16; ++i) {
    int idx = threadIdx.x + i * 256;
    int rr = idx >> 6, cc = idx & 63;  // rr: dv-off, cc: l-off
    Vt[((size_t)bh * 128 + d0 + rr) * 2048 + l0 + cc] = f2bf(tile[cc][rr]);
  }
}

// ---------------- GEMM: C(MxN) = A(MxK bf16, row-stride lda) * Bt(NxK bf16)^T ----------------
DEV void ep_set(u16* E, int i, float v) { E[i] = f2bf(v); }
DEV void ep_set(float* E, int i, float v) { E[i] = v; }

template <typename OT>
__global__ __launch_bounds__(256) void gemm_bt(const u16* __restrict__ A, int lda,
                                               const u16* __restrict__ Bt,
                                               OT* __restrict__ C, int ldc,
                                               int M, int N, int K) {
  __shared__ u16 smem_ab[2 * 128 * 32];   // As | Bs (contiguous 16KB; reused by epilogue)
  u16* As = smem_ab;
  u16* Bs = smem_ab + 128 * 32;
  const int tid = threadIdx.x;
  const int lane = tid & 63;
  const int w = tid >> 6;       // 0..3
  const int quad = lane >> 4;   // 0..3
  const int l15 = lane & 15;
  const int m0 = blockIdx.y * 128;
  const int n0 = blockIdx.x * 128;
  const int wm = (w & 1) * 64;
  const int wn = (w >> 1) * 64;

  f32x4 acc[4][4] = {};

  for (int k0 = 0; k0 < K; k0 += 32) {
#pragma unroll
    for (int it = 0; it < 2; ++it) {
      int ca = w * 128 + it * 64;       // wave-uniform base chunk
      int c = ca + lane;
      int row = c >> 2, kc = (c & 3) * 8;
      gl_lds16(A + (size_t)(m0 + row) * lda + k0 + kc, &As[ca * 8]);
      gl_lds16(Bt + (size_t)(n0 + row) * K + k0 + kc, &Bs[ca * 8]);
    }
    __syncthreads();   // waits vmcnt(0) for global_load_lds
    bf16x8 af[4], bf[4];
#pragma unroll
    for (int mt = 0; mt < 4; ++mt) af[mt] = *(const bf16x8*)&As[(wm + mt * 16 + l15) * 32 + quad * 8];
#pragma unroll
    for (int nt = 0; nt < 4; ++nt) bf[nt] = *(const bf16x8*)&Bs[(wn + nt * 16 + l15) * 32 + quad * 8];
#pragma unroll
    for (int mt = 0; mt < 4; ++mt)
#pragma unroll
      for (int nt = 0; nt < 4; ++nt)
        acc[mt][nt] = __builtin_amdgcn_mfma_f32_16x16x32_bf16(af[mt], bf[nt], acc[mt][nt], 0, 0, 0);
    __syncthreads();
  }

  // wide-store epilogue through LDS (smem_ab free after final barrier).
  // Wave-private region -> only lgkmcnt fences needed (DS ops are in-order per wave).
  OT* Ew = ((OT*)smem_ab) + w * 1024;   // 16 rows x 64 cols per wave
#pragma unroll
  for (int mt = 0; mt < 4; ++mt) {
#pragma unroll
    for (int nt = 0; nt < 4; ++nt)
#pragma unroll
      for (int r = 0; r < 4; ++r)
        ep_set(Ew, (quad * 4 + r) * 64 + nt * 16 + l15, acc[mt][nt][r]);
    asm volatile("s_waitcnt lgkmcnt(0)" ::: "memory");
#pragma unroll
    for (int it2 = 0; it2 < 4; ++it2) {
      int row_i = it2 * 4 + quad;
      int colg = n0 + wn + l15 * 4;
      if (colg < N) {   // only trims for the N=64 (W_KR) GEMM
        size_t off = (size_t)(m0 + wm + mt * 16 + row_i) * ldc + colg;
        if constexpr (sizeof(OT) == 2) {
          *(u16x4*)&C[off] = *(const u16x4*)&Ew[row_i * 64 + l15 * 4];
        } else {
          *(float4*)&C[off] = *(const float4*)&Ew[row_i * 64 + l15 * 4];
        }
      }
    }
  }
}

// ---------------- build q / k: rope + concat + L2-normalize, one wave per (token, head) ----------------
__global__ __launch_bounds__(256) void build_q(const u16* __restrict__ qcr,  // (B*L, 3072): qc|qr
                                               const float* __restrict__ s_qk,
                                               u16* __restrict__ qn) {
  const int wid = blockIdx.x * 4 + (threadIdx.x >> 6);
  const int lane = threadIdx.x & 63;
  const int token = wid >> 4;     // b*L + l
  const int h = wid & 15;
  const int b = token >> 11;
  const int l = token & 2047;
  float v0 = bf2f(qcr[(size_t)token * 3072 + h * 128 + lane]);
  float v1 = bf2f(qcr[(size_t)token * 3072 + h * 128 + 64 + lane]);
  int j = lane & 31;
  float freq = powf(10000.f, -(float)j * (1.f / 32.f));
  float ang = (float)l * freq;
  float cs = cosf(ang), sn = sinf(ang);
  float xr = bf2f(qcr[(size_t)token * 3072 + 2048 + h * 64 + lane]);
  float xo = bf2f(qcr[(size_t)token * 3072 + 2048 + h * 64 + (lane ^ 32)]);
  float v2 = (lane < 32) ? (xr * cs - xo * sn) : (xr * cs + xo * sn);
  float ss = v0 * v0 + v1 * v1 + v2 * v2;
#pragma unroll
  for (int off = 1; off < 64; off <<= 1) ss += __shfl_xor(ss, off, 64);
  float scale = s_qk[0] / fmaxf(sqrtf(ss), 1e-12f);
  u16* out = qn + (((size_t)(b * 16 + h) * 2048) + l) * 192;
  out[lane] = f2bf(v0 * scale);
  out[64 + lane] = f2bf(v1 * scale);
  out[128 + lane] = f2bf(v2 * scale);
}

__global__ __launch_bounds__(256) void build_k(const u16* __restrict__ kcv,  // (B*L, 4096): kc|v
                                               const u16* __restrict__ krr,  // (B*L, 64)
                                               u16* __restrict__ kn) {
  const int wid = blockIdx.x * 4 + (threadIdx.x >> 6);
  const int lane = threadIdx.x & 63;
  const int token = wid >> 4;
  const int h = wid & 15;
  const int b = token >> 11;
  const int l = token & 2047;
  float v0 = bf2f(kcv[(size_t)token * 4096 + h * 128 + lane]);
  float v1 = bf2f(kcv[(size_t)token * 4096 + h * 128 + 64 + lane]);
  int j = lane & 31;
  float freq = powf(10000.f, -(float)j * (1.f / 32.f));
  float ang = (float)l * freq;
  float cs = cosf(ang), sn = sinf(ang);
  float xr = bf2f(krr[(size_t)token * 64 + lane]);
  float xo = bf2f(krr[(size_t)token * 64 + (lane ^ 32)]);
  float v2 = (lane < 32) ? (xr * cs - xo * sn) : (xr * cs + xo * sn);
  float ss = v0 * v0 + v1 * v1 + v2 * v2;
#pragma unroll
  for (int off = 1; off < 64; off <<= 1) ss += __shfl_xor(ss, off, 64);
  float scale = 1.0f / fmaxf(sqrtf(ss), 1e-12f);
  u16* out = kn + (((size_t)(b * 16 + h) * 2048) + l) * 192;
  out[lane] = f2bf(v0 * scale);
  out[64 + lane] = f2bf(v1 * scale);
  out[128 + lane] = f2bf(v2 * scale);
}

// ---------------- flash attention (causal), 512 thr ----------------
// 32-key KV tiles, double-buffered LDS with prefetch-after-barrier: loads for
// tile kt+1 overlap compute of tile kt (vmcnt-only; no false lgkm dependency).
// LDS 50176B -> 3 blocks/CU. Wide O store via LDS transpose (full-line writes).
__global__ __launch_bounds__(512, 6) void flash_attn(const u16* __restrict__ Q,   // (B,H,L,192)
                                                     const u16* __restrict__ Kn,  // (B,H,L,192)
                                                     const u16* __restrict__ Vt,  // (B,H,128,L)
                                                     u16* __restrict__ O) {       // (B,L,2048)
  constexpr int L = 2048, DQK = 192, DV = 128;
  constexpr int PSTR = 36;
  __shared__ u16 smem[25088];          // Ks[2][32*192] | Vs[2][128*32] | Ps[8*16*36]
  u16* KsBuf = smem;                   // 2 x 6144
  u16* VsBuf = smem + 12288;           // 2 x 4096
  u16* Ps    = smem + 20480;           // 4608
  const int tid = threadIdx.x;
  const int lane = tid & 63;
  const int w = tid >> 6;       // 0..7, q-row group
  const int quad = lane >> 4;
  const int l15 = lane & 15;
  // block mapping: all 16 qt of one bh on one XCD (lin%8 heuristic), long blocks first
  const int lin = blockIdx.x;
  const int xcd = lin & 7;
  const int g = lin >> 3;
  const int bh = ((g >> 4) << 3) | xcd;
  const int qt = 15 - (g & 15);
  const int b = bh >> 4, h = bh & 15;

  const u16* Qg = Q + ((size_t)bh * L + qt * 128) * DQK;
  const u16* Kg = Kn + (size_t)bh * L * DQK;
  const u16* Vg = Vt + (size_t)bh * DV * L;

  // stage one 32-key K/V tile into buffer bufi.
  // K: 32 rows x 24 chunks = 768 chunks (16B), swizzled phys_c = c ^ (r&7).
  // V: 128 dv x 4 chunks = 512 chunks, linear (stride 16 dwords is bank-clean).
  auto stage = [&](int kt2, int bufi) {
    u16* KsB = KsBuf + bufi * 6144;
    u16* VsB = VsBuf + bufi * 4096;
#pragma unroll
    for (int it = 0; it < 3; ++it) {
      int B0 = it * 512 + w * 64;            // wave-uniform
      if (B0 < 768) {
        int p = B0 + lane;
        int r = p / 24, cp = p % 24;
        int c = cp ^ (r & 7);
        gl_lds16(Kg + (size_t)(kt2 * 32 + r) * DQK + c * 8, &KsB[B0 * 8]);
      } else if (B0 < 1280) {
        int q = B0 - 768 + lane;
        int dv = q >> 2, cp = q & 3;
        gl_lds16(Vg + (size_t)dv * L + kt2 * 32 + cp * 8, &VsB[(B0 - 768) * 8]);
      }
    }
  };

  // Q fragments in registers: wave w owns q rows w*16..w*16+15
  bf16x8 qf[6];
#pragma unroll
  for (int kd = 0; kd < 6; ++kd)
    qf[kd] = *(const bf16x8*)&Qg[(w * 16 + l15) * DQK + kd * 32 + quad * 8];

  f32x4 oacc[8] = {};
  float mrow[4], lrow[4];
#pragma unroll
  for (int r = 0; r < 4; ++r) { mrow[r] = -1e30f; lrow[r] = 0.f; }

  const int nkv = 4 * qt + 4;   // 32-key tiles
  stage(0, 0);
  __syncthreads();

  for (int kt = 0; kt < nkv; ++kt) {
    const int cur = kt & 1;
    if (kt + 1 < nkv) stage(kt + 1, cur ^ 1);   // prefetch overlaps compute below
    const u16* KsC = KsBuf + cur * 6144;
    const u16* VsC = VsBuf + cur * 4096;

    // S (16q x 32k) per wave
    f32x4 s[2] = {};
#pragma unroll
    for (int kd = 0; kd < 6; ++kd) {
      bf16x8 a = qf[kd];
#pragma unroll
      for (int nt = 0; nt < 2; ++nt) {
        int row = nt * 16 + l15;
        int cp = (kd * 4 + quad) ^ (l15 & 7);
        bf16x8 bb = *(const bf16x8*)&KsC[row * DQK + cp * 8];
        s[nt] = __builtin_amdgcn_mfma_f32_16x16x32_bf16(a, bb, s[nt], 0, 0, 0);
      }
    }

    // causal mask + online softmax (rows quad*4+r, cols l15+16*nt)
    const int qrow_base = qt * 128 + w * 16 + quad * 4;
    const int kcol = kt * 32 + l15;
    float pv[2][4];  // [nt][r]
#pragma unroll
    for (int r = 0; r < 4; ++r) {
      float mx = -1e30f;
#pragma unroll
      for (int nt = 0; nt < 2; ++nt) {
        float sv = s[nt][r];
        if (kcol + nt * 16 > qrow_base + r) sv = -1e30f;
        mx = fmaxf(mx, sv);
        pv[nt][r] = sv;
      }
#pragma unroll
      for (int off = 1; off < 16; off <<= 1) mx = fmaxf(mx, __shfl_xor(mx, off, 64));
      float mnew = fmaxf(mrow[r], mx);
      float alpha = __expf(mrow[r] - mnew);
      float rs = 0.f;
#pragma unroll
      for (int nt = 0; nt < 2; ++nt) {
        float p = __expf(pv[nt][r] - mnew);
        pv[nt][r] = p;
        rs += p;
      }
#pragma unroll
      for (int off = 1; off < 16; off <<= 1) rs += __shfl_xor(rs, off, 64);
      lrow[r] = lrow[r] * alpha + rs;
      mrow[r] = mnew;
#pragma unroll
      for (int nt2 = 0; nt2 < 8; ++nt2) oacc[nt2][r] *= alpha;
    }

    // P (16x32) -> per-wave LDS (C-layout scatter) -> A-layout read
    u16* Pw = &Ps[w * 16 * PSTR];
#pragma unroll
    for (int nt = 0; nt < 2; ++nt)
#pragma unroll
      for (int r = 0; r < 4; ++r)
        Pw[(quad * 4 + r) * PSTR + nt * 16 + l15] = f2bf(pv[nt][r]);
    asm volatile("s_waitcnt lgkmcnt(0)" ::: "memory");  // within-wave WAR/RAW order
    bf16x8 p = *(const bf16x8*)&Pw[l15 * PSTR + quad * 8];
#pragma unroll
    for (int nt2 = 0; nt2 < 8; ++nt2) {
      int dv = nt2 * 16 + l15;
      bf16x8 vv = *(const bf16x8*)&VsC[dv * 32 + quad * 8];
      oacc[nt2] = __builtin_amdgcn_mfma_f32_16x16x32_bf16(p, vv, oacc[nt2], 0, 0, 0);
    }
    __syncthreads();  // drains prefetch (vmcnt) + frees cur buffer
  }

  // epilogue: wide O store via LDS transpose. smem front is free after barrier.
  __syncthreads();
  u16* Ew = smem + w * 2048;    // 16 rows x 128 cols per wave (8 waves = 32KB <= 40KB)
#pragma unroll
  for (int nt2 = 0; nt2 < 8; ++nt2)
#pragma unroll
    for (int r = 0; r < 4; ++r)
      Ew[(quad * 4 + r) * 128 + nt2 * 16 + l15] = f2bf(oacc[nt2][r] / lrow[r]);
  asm volatile("s_waitcnt lgkmcnt(0)" ::: "memory");
#pragma unroll
  for (int it2 = 0; it2 < 4; ++it2) {
    int row_i = it2 * 4 + quad;
    int lg = qt * 128 + w * 16 + row_i;
    uint4 v = *(const uint4*)&Ew[row_i * 128 + l15 * 8];
    *(uint4*)&O[((size_t)b * L + lg) * 2048 + h * 128 + l15 * 8] = v;
  }
}

// ---------------- launcher ----------------
extern "C" void kernel_launch(void* const* d_in, const int* in_sizes, int n_in,
                              void* d_out, int out_size, void* d_ws, size_t ws_size,
                              hipStream_t stream) {
  const float* x     = (const float*)d_in[0];
  const float* W_DKV = (const float*)d_in[1];
  const float* W_UK  = (const float*)d_in[2];
  const float* W_UV  = (const float*)d_in[3];
  const float* W_DQ  = (const float*)d_in[4];
  const float* W_UQ  = (const float*)d_in[5];
  const float* W_QR  = (const float*)d_in[6];
  const float* W_KR  = (const float*)d_in[7];
  const float* W_O   = (const float*)d_in[8];
  const float* s_qk  = (const float*)d_in[9];

  char* base = (char*)d_ws;
  // static layout (bytes) — high-water mark 232,259,584 B (221.5 MiB):
  u16* xb     = (u16*)(base);                        // [0, 33,554,432)           dead after G_KR
  u16* WtDKVQ = (u16*)(base + (size_t)33554432);     // [.., 41,943,040)  8.39 MB dead after G1
  u16* WtUKV  = (u16*)(base + (size_t)41943040);     // [.., 58,720,256) 16.78 MB dead after G2
  u16* WtUQR  = (u16*)(base + (size_t)58720256);     // [.., 71,303,168) 12.58 MB dead after G3
  u16* WtKR   = (u16*)(base + (size_t)71303168);     // [.., 71,827,456)  0.52 MB dead after G_KR
  u16* WtO    = (u16*)(base + (size_t)71827456);     // [.., 80,216,064)  8.39 MB live to end
  u16* ckvq   = (u16*)(base + (size_t)80216064);     // [.., 113,770,496) 33.55 MB dead after G3
  u16* kcv    = (u16*)(base + (size_t)113770496);    // [.., 180,879,360) 67.11 MB dead after transpose_v
  u16* qcr    = (u16*)(base + (size_t)180879360);    // [.., 231,211,008) 50.33 MB dead after build_q
  u16* kr     = (u16*)(base + (size_t)231211008);    // [.., 232,259,584)  1.05 MB
  // aliases (each writer runs strictly after the aliased region's last reader):
  u16* qn = (u16*)(base);      // 50.33 MB over xb+WtDKVQ+WtUKV (all dead before build_q)
  u16* kn = qcr;               // 50.33 MB, exact size match; build_k runs after build_q
  u16* Vt = ckvq;              // 33.55 MB over ckvq (dead after G3)
  u16* O  = kcv;               // 33.55 MB over kcv head (dead after transpose_v)

  // 1) casts / weight transposes (into merged layouts)
  cast_f32_bf16<<<16384, 256, 0, stream>>>(x, xb, 8192 * 2048 / 4);
  transpose_cast<<<dim3(16, 32), 256, 0, stream>>>(W_DKV, WtDKVQ,                  2048, 1024);
  transpose_cast<<<dim3(16, 32), 256, 0, stream>>>(W_DQ,  WtDKVQ + 1024 * 2048,    2048, 1024);
  transpose_cast<<<dim3(32, 16), 256, 0, stream>>>(W_UK,  WtUKV,                   1024, 2048);
  transpose_cast<<<dim3(32, 16), 256, 0, stream>>>(W_UV,  WtUKV + 2048 * 1024,     1024, 2048);
  transpose_cast<<<dim3(32, 16), 256, 0, stream>>>(W_UQ,  WtUQR,                   1024, 2048);
  transpose_cast<<<dim3(16, 16), 256, 0, stream>>>(W_QR,  WtUQR + 2048 * 1024,     1024, 1024);
  transpose_cast<<<dim3(1, 32),  256, 0, stream>>>(W_KR,  WtKR,                    2048, 64);
  transpose_cast<<<dim3(32, 32), 256, 0, stream>>>(W_O,   WtO,                     2048, 2048);

  // 2) merged projection GEMMs
  gemm_bt<u16><<<dim3(16, 64), 256, 0, stream>>>(xb, 2048, WtDKVQ, ckvq, 2048, 8192, 2048, 2048);
  gemm_bt<u16><<<dim3(1, 64),  256, 0, stream>>>(xb, 2048, WtKR, kr, 64, 8192, 64, 2048);
  gemm_bt<u16><<<dim3(32, 64), 256, 0, stream>>>(ckvq, 2048, WtUKV, kcv, 4096, 8192, 4096, 1024);
  gemm_bt<u16><<<dim3(24, 64), 256, 0, stream>>>(ckvq + 1024, 2048, WtUQR, qcr, 3072, 8192, 3072, 1024);

  // 3) rope + concat + normalize (build_q consumes qcr, THEN build_k writes kn over it)
  build_q<<<32768, 256, 0, stream>>>(qcr, s_qk, qn);
  build_k<<<32768, 256, 0, stream>>>(kcv, kr, kn);

  // 4) V transpose (Vt over dead ckvq region)
  transpose_v<<<dim3(32, 2, 64), 256, 0, stream>>>(kcv, Vt);

  // 5) attention (O over dead kcv head)
  flash_attn<<<dim3(1024), 512, 0, stream>>>(qn, kn, Vt, O);

  // 6) output projection -> fp32 d_out
  gemm_bt<float><<<dim3(16, 64), 256, 0, stream>>>(O, 2048, WtO, (float*)d_out, 2048, 8192, 2048, 2048);
}